// Round 14
// baseline (419.141 us; speedup 1.0000x reference)
//
#include <hip/hip_runtime.h>
#include <hip/hip_bf16.h>
#include <math.h>

#define NM 65536
#define NB 128
#define NU 256
#define ND 512

// ---- output layout (flat f32, reference return order) ----
constexpr size_t OUT_READ = 0;                      // [B,U]    32768
constexpr size_t OUT_MEM  = 32768;                  // [M,U]    16777216
constexpr size_t OUT_CWU  = OUT_MEM + 16777216;     // [M,B]    8388608
constexpr size_t OUT_CWLU = OUT_CWU + 8388608;      // [M,B]
constexpr size_t OUT_CWR  = OUT_CWLU + 8388608;     // [M,B]
constexpr size_t OUT_KEY  = OUT_CWR + 8388608;      // [B,U]
constexpr size_t OUT_CC   = OUT_KEY + 32768;        // [B,U]

// ---- ws layout (bytes) ----
constexpr size_t WS_KLNT   = 0;        // 32768 f32 (klnT[u][b])
constexpr size_t WS_MINENC = 131072;   // 128 u64
constexpr size_t WS_MINS   = 132096;   // 128 f32
constexpr size_t WS_ISTAR  = 132608;   // 1 u32
constexpr size_t WS_PART   = 135168;   // 512 * 16384 f32 read-partials (32 MB)

typedef __attribute__((ext_vector_type(8))) short short8v;   // 8 bf16 (4 VGPRs)
typedef __attribute__((ext_vector_type(4))) float floatx4;

__device__ __forceinline__ unsigned fenc(float x) {
    unsigned u = __float_as_uint(x);
    return (u & 0x80000000u) ? ~u : (u | 0x80000000u);
}
__device__ __forceinline__ float fdec(unsigned e) {
    unsigned u = (e & 0x80000000u) ? (e ^ 0x80000000u) : ~e;
    return __uint_as_float(u);
}
__device__ __forceinline__ float sigm(float x) { return 1.0f / (1.0f + expf(-x)); }
__device__ __forceinline__ unsigned short f2b(float f) {
    __hip_bfloat16 h = __float2bfloat16(f);      // RNE
    return *reinterpret_cast<unsigned short*>(&h);
}

// ---------------- K1: LSTM controller + normalized keys (R12, numerics anchor) ----------------
__global__ __launch_bounds__(256) void k_lstm(
    const float* __restrict__ xin_g, const float* __restrict__ r_tm1,
    const float* __restrict__ h_tm1, const float* __restrict__ cc_tm1,
    const float* __restrict__ Wk, const float* __restrict__ Wr,
    const float* __restrict__ bias, float* __restrict__ out,
    float* __restrict__ klnT, unsigned long long* __restrict__ minenc)
{
    const int b = blockIdx.x, t = threadIdx.x;
    __shared__ float xin[ND + NU];
    __shared__ float hh[NU];
    __shared__ float red[NU];
    for (int k = t; k < ND; k += 256) xin[k] = xin_g[b * ND + k];
    xin[ND + t] = r_tm1[b * NU + t];
    hh[t] = h_tm1[b * NU + t];
    out[OUT_READ + b * NU + t] = 0.f;              // zero read region each launch
    if (b == 0 && t < NB) minenc[t] = ~0ULL;       // init argmin atomics
    __syncthreads();

    float zi = bias[t], zf = bias[NU + t], zc = bias[2 * NU + t], zo = bias[3 * NU + t];
    #pragma unroll 4
    for (int k = 0; k < ND + NU; ++k) {
        const float x = xin[k];
        const float* w = Wk + (size_t)k * (4 * NU);
        zi += x * w[t]; zf += x * w[NU + t]; zc += x * w[2 * NU + t]; zo += x * w[3 * NU + t];
    }
    #pragma unroll 4
    for (int k = 0; k < NU; ++k) {
        const float x = hh[k];
        const float* w = Wr + (size_t)k * (4 * NU);
        zi += x * w[t]; zf += x * w[NU + t]; zc += x * w[2 * NU + t]; zo += x * w[3 * NU + t];
    }
    const float gi = sigm(zi), gf = sigm(zf), gc = tanhf(zc), go = sigm(zo);
    const float cold = cc_tm1[b * NU + t];
    const float cn = __fadd_rn(__fmul_rn(gf, cold), __fmul_rn(gi, gc));
    const float hn = __fmul_rn(go, tanhf(cn));
    out[OUT_KEY + b * NU + t] = hn;
    out[OUT_CC + b * NU + t] = cn;
    red[t] = hn * hn;
    __syncthreads();
    for (int s = 128; s > 0; s >>= 1) { if (t < s) red[t] += red[t + s]; __syncthreads(); }
    const float nrm = sqrtf(fmaxf(red[0], 1e-12f));
    klnT[t * NB + b] = hn / nrm;   // transposed [u][b]
}

// ------------- K2 v7: R12 K-loop + R9's verified two-half epilogue -------------
// ONLY change vs R12: dot tile spilled in two 64-slot halves through the 32 KB
// stage region -> LDS 74->33 KB -> 4 blocks/CU (occupancy doubles). All FMA /
// softmax / usage / min sequences token-identical -> bit-identical outputs.
__global__ __launch_bounds__(256) void k_dot(
    const float* __restrict__ mT, const float* __restrict__ klnT,
    const float* __restrict__ cwr_t, const float* __restrict__ cwlu_t,
    const float* __restrict__ cwu_t, const float* __restrict__ wgp,
    float* __restrict__ out, unsigned long long* __restrict__ minenc)
{
    __shared__ float smem[8192];       // 32 KB: stage buffers; reused as half-tile spill
    __shared__ float rn_s[128];
    const int t = threadIdx.x, w = t >> 6, l = t & 63;
    const int tx = t & 15, ty = t >> 4;
    const int b0a = tx * 4, b0b = 64 + tx * 4;   // split b-columns (conflict-free kv reads)
    const int s0 = ty * 8;
    const int sb = blockIdx.x * 128;

    // ---- phase 0: row norms (bit-identical: lane-l float4 + xor tree) ----
    #pragma unroll 4
    for (int i = 0; i < 32; ++i) {
        const int s = w * 32 + i;
        const float4 mv = *(const float4*)(mT + (size_t)(sb + s) * NU + l * 4);
        float ss = mv.x * mv.x + mv.y * mv.y + mv.z * mv.z + mv.w * mv.w;
        #pragma unroll
        for (int d = 1; d < 64; d <<= 1) ss += __shfl_xor(ss, d);
        if (l == 0) rn_s[s] = sqrtf(fmaxf(ss, 1e-12f));   // barriers intervene before cross-wave read
    }

    // ---- phase 1: GEMM dot[s][b] = sum_u m[s][u] * kln[u][b] (R12 loop, unchanged) ----
    const int sl = t & 127, ug = t >> 7;       // ms stage: slot sl, u-halves
    const int ku_ = t >> 4, kb = (t & 15) * 4; // kl stage

    float acc[8][8];
    #pragma unroll
    for (int i = 0; i < 8; ++i)
        #pragma unroll
        for (int j = 0; j < 8; ++j) acc[i][j] = 0.f;

    float4 gm[2], gk[2];
    #pragma unroll
    for (int i = 0; i < 2; ++i) {
        gm[i] = *(const float4*)(mT + (size_t)(sb + sl) * NU + (ug + 2 * i) * 4);
        gk[i] = *(const float4*)(klnT + (size_t)ku_ * NB + kb + i * 64);
    }
    for (int c = 0; c < 16; ++c) {
        const int mo = (c & 1) * 2048;          // ms buffer offset
        const int ko = 4096 + (c & 1) * 2048;   // kl buffer offset
        #pragma unroll
        for (int i = 0; i < 2; ++i) {
            const int uo = (ug + 2 * i) * 4;
            smem[mo + (uo + 0) * 128 + sl] = gm[i].x;
            smem[mo + (uo + 1) * 128 + sl] = gm[i].y;
            smem[mo + (uo + 2) * 128 + sl] = gm[i].z;
            smem[mo + (uo + 3) * 128 + sl] = gm[i].w;
            *(float4*)&smem[ko + ku_ * 128 + kb + i * 64] = gk[i];
        }
        __syncthreads();
        if (c < 15) {   // prefetch next chunk into registers (overlaps compute)
            const int uc = (c + 1) * 16;
            #pragma unroll
            for (int i = 0; i < 2; ++i) {
                gm[i] = *(const float4*)(mT + (size_t)(sb + sl) * NU + uc + (ug + 2 * i) * 4);
                gk[i] = *(const float4*)(klnT + (size_t)(uc + ku_) * NB + kb + i * 64);
            }
        }
        #pragma unroll 4
        for (int u = 0; u < 16; ++u) {
            const float4 sv0 = *(const float4*)&smem[mo + u * 128 + s0];
            const float4 sv1 = *(const float4*)&smem[mo + u * 128 + s0 + 4];
            const float4 kv0 = *(const float4*)&smem[ko + u * 128 + b0a];   // 256B run: conflict-free
            const float4 kv1 = *(const float4*)&smem[ko + u * 128 + b0b];   // 256B run: conflict-free
            const float sv[8] = {sv0.x, sv0.y, sv0.z, sv0.w, sv1.x, sv1.y, sv1.z, sv1.w};
            const float kv[8] = {kv0.x, kv0.y, kv0.z, kv0.w, kv1.x, kv1.y, kv1.z, kv1.w};
            #pragma unroll
            for (int i = 0; i < 8; ++i)
                #pragma unroll
                for (int j = 0; j < 8; ++j)
                    acc[i][j] += sv[i] * kv[j];   // single fmac chain ascending u per (s,b)
        }
        __syncthreads();
    }

    // ---- epilogue: two 64-slot halves through the 32 KB spill (R9-verified) ----
    const float wg = sigm(wgp[0]);
    const float omw = __fsub_rn(1.f, wg);
    unsigned long long lmin0 = ~0ULL, lmin1 = ~0ULL;
    #pragma unroll
    for (int h = 0; h < 2; ++h) {
        __syncthreads();               // stage buffers / previous half free
        if ((ty >> 3) == h) {          // holders of slots [64h, 64h+64) spill
            const int ls0 = s0 & 63;
            #pragma unroll
            for (int i = 0; i < 8; ++i) {
                *(float4*)&smem[(ls0 + i) * 128 + b0a] = make_float4(acc[i][0], acc[i][1], acc[i][2], acc[i][3]);
                *(float4*)&smem[(ls0 + i) * 128 + b0b] = make_float4(acc[i][4], acc[i][5], acc[i][6], acc[i][7]);
            }
        }
        __syncthreads();
        #pragma unroll 2
        for (int i = 0; i < 16; ++i) {
            const int ls = w * 16 + i;
            const int s = h * 64 + ls;
            const int m = sb + s;
            const float2 dv = *(const float2*)&smem[ls * 128 + 2 * l];
            const float rnv = rn_s[s];
            const float2 wrt = ((const float2*)(cwr_t + (size_t)m * NB))[l];
            const float2 wlu = ((const float2*)(cwlu_t + (size_t)m * NB))[l];
            const float2 wut = ((const float2*)(cwu_t + (size_t)m * NB))[l];
            const float c0 = dv.x / rnv, c1 = dv.y / rnv;
            float mx = fmaxf(c0, c1);
            #pragma unroll
            for (int d = 1; d < 64; d <<= 1) mx = fmaxf(mx, __shfl_xor(mx, d));
            const float e0 = expf(c0 - mx), e1 = expf(c1 - mx);
            float sm = e0 + e1;
            #pragma unroll
            for (int d = 1; d < 64; d <<= 1) sm += __shfl_xor(sm, d);
            const float w0 = e0 / sm, w1 = e1 / sm;
            const float cww0 = __fadd_rn(__fadd_rn(__fmul_rn(wg, wrt.x), omw), wlu.x);
            const float cww1 = __fadd_rn(__fadd_rn(__fmul_rn(wg, wrt.y), omw), wlu.y);
            const float cu0 = __fadd_rn(__fadd_rn(__fmul_rn(0.95f, wut.x), w0), cww0);
            const float cu1 = __fadd_rn(__fadd_rn(__fmul_rn(0.95f, wut.y), w1), cww1);
            ((float2*)(out + OUT_CWR))[(size_t)m * 64 + l] = make_float2(w0, w1);
            ((float2*)(out + OUT_CWU))[(size_t)m * 64 + l] = make_float2(cu0, cu1);
            const unsigned long long e0u = (((unsigned long long)fenc(cu0)) << 32) | (unsigned)m;
            const unsigned long long e1u = (((unsigned long long)fenc(cu1)) << 32) | (unsigned)m;
            lmin0 = (e0u < lmin0) ? e0u : lmin0;   // min accumulation order-free (exact)
            lmin1 = (e1u < lmin1) ? e1u : lmin1;
        }
    }
    atomicMin(&minenc[2 * l], lmin0);
    atomicMin(&minenc[2 * l + 1], lmin1);
}

// ---------------- K3: global argmin (first-occurrence) ----------------
__global__ void k_argmin(const unsigned long long* __restrict__ minenc,
                         float* __restrict__ mins, unsigned* __restrict__ istar)
{
    __shared__ unsigned long long red[NB];
    const int t = threadIdx.x;
    const unsigned long long e = minenc[t];
    const unsigned enc32 = (unsigned)(e >> 32);
    mins[t] = fdec(enc32);
    red[t] = (((unsigned long long)enc32) << 32) | (unsigned)t;
    __syncthreads();
    for (int s = 64; s > 0; s >>= 1) {
        if (t < s) { const unsigned long long o = red[t + s]; if (o < red[t]) red[t] = o; }
        __syncthreads();
    }
    if (t == 0) {
        const unsigned bstar = (unsigned)(red[0] & 0xFFFFFFFFu);
        istar[0] = (unsigned)(minenc[bstar] & 0xFFFFFFFFu);
    }
}

// -------- K4a: memory = cww @ key (bf16 MFMA) + 128*keep*m (f32) + c_wlu (R12) --------
__global__ __launch_bounds__(256, 2) void k_mem(
    const float* __restrict__ mT,
    const float* __restrict__ cwr_t, const float* __restrict__ cwlu_t,
    const float* __restrict__ wgp, const float* __restrict__ mins,
    const unsigned* __restrict__ istar_p, float* __restrict__ out)
{
    __shared__ alignas(16) unsigned short cwwb[128 * 136];   // [s][b] bf16, stride 136
    __shared__ alignas(16) unsigned short keyT[128 * 136];   // [u_local][b] bf16; reused as f32 scratch
    const int t = threadIdx.x, w = t >> 6, l = t & 63;
    const int sb = blockIdx.x * 128;
    const float wg = sigm(wgp[0]);
    const float omw = __fsub_rn(1.f, wg);
    const int istar = (int)istar_p[0];

    // ---- S1: cww -> bf16 LDS; c_wlu -> global (exact f32 chain) ----
    {
        const int srow = t >> 5;
        const int bc = (t & 31) * 4;
        for (int it = 0; it < 16; ++it) {
            const int s = it * 8 + srow;
            const size_t row = (size_t)(sb + s) * NB + bc;
            const float4 wr = *(const float4*)(cwr_t + row);
            const float4 lu = *(const float4*)(cwlu_t + row);
            const float4 wu = *(const float4*)(out + OUT_CWU + row);
            float4 cw;
            cw.x = __fadd_rn(__fadd_rn(__fmul_rn(wg, wr.x), omw), lu.x);
            cw.y = __fadd_rn(__fadd_rn(__fmul_rn(wg, wr.y), omw), lu.y);
            cw.z = __fadd_rn(__fadd_rn(__fmul_rn(wg, wr.z), omw), lu.z);
            cw.w = __fadd_rn(__fadd_rn(__fmul_rn(wg, wr.w), omw), lu.w);
            ushort4 pk;
            pk.x = f2b(cw.x); pk.y = f2b(cw.y); pk.z = f2b(cw.z); pk.w = f2b(cw.w);
            *(ushort4*)&cwwb[s * 136 + bc] = pk;
            const float4 mb = *(const float4*)(mins + bc);
            float4 wl;
            wl.x = (wu.x <= mb.x) ? 1.f : 0.f;
            wl.y = (wu.y <= mb.y) ? 1.f : 0.f;
            wl.z = (wu.z <= mb.z) ? 1.f : 0.f;
            wl.w = (wu.w <= mb.w) ? 1.f : 0.f;
            *(float4*)(out + OUT_CWLU + row) = wl;
        }
    }

    const int rk = (l >> 4) * 8;
    const int rr = l & 15;

    for (int uh = 0; uh < 2; ++uh) {
        if (uh) __syncthreads();     // epilogue scratch reads done before re-staging keyT
        // ---- S2: keyT half uh: key[b][u] f32 -> bf16 LDS [u_local][b] ----
        {
            const int br = t >> 5;
            const int ko = (t & 31) * 4;
            for (int it = 0; it < 16; ++it) {
                const int b = it * 8 + br;
                const float4 kv = *(const float4*)(out + OUT_KEY + (size_t)b * NU + uh * 128 + ko);
                keyT[(ko + 0) * 136 + b] = f2b(kv.x);
                keyT[(ko + 1) * 136 + b] = f2b(kv.y);
                keyT[(ko + 2) * 136 + b] = f2b(kv.z);
                keyT[(ko + 3) * 136 + b] = f2b(kv.w);
            }
        }
        __syncthreads();

        // ---- MFMA: wave w -> s-tiles {2w, 2w+1}; 8 u-tiles; K=128 in 4 chunks ----
        floatx4 acc0[8], acc1[8];
        #pragma unroll
        for (int ut = 0; ut < 8; ++ut) {
            acc0[ut] = (floatx4){0.f, 0.f, 0.f, 0.f};
            acc1[ut] = (floatx4){0.f, 0.f, 0.f, 0.f};
        }
        #pragma unroll
        for (int kc = 0; kc < 4; ++kc) {
            const short8v a0 = *(const short8v*)&cwwb[(w * 32 + rr) * 136 + kc * 32 + rk];
            const short8v a1 = *(const short8v*)&cwwb[(w * 32 + 16 + rr) * 136 + kc * 32 + rk];
            #pragma unroll
            for (int ut = 0; ut < 8; ++ut) {
                const short8v bf = *(const short8v*)&keyT[(ut * 16 + rr) * 136 + kc * 32 + rk];
                acc0[ut] = __builtin_amdgcn_mfma_f32_16x16x32_bf16(a0, bf, acc0[ut], 0, 0, 0);
                acc1[ut] = __builtin_amdgcn_mfma_f32_16x16x32_bf16(a1, bf, acc1[ut], 0, 0, 0);
            }
        }

        // ---- epilogue: transpose D via per-wave scratch (keyT region), float4 I/O ----
        __syncthreads();                           // all waves done reading keyT
        float* scr = (float*)keyT + w * 2112;      // [16][132] f32, wave-private
        const int erow = l >> 2, ecb = (l & 3) * 4;
        #pragma unroll
        for (int bt = 0; bt < 2; ++bt) {
            #pragma unroll
            for (int ut = 0; ut < 8; ++ut)
                #pragma unroll
                for (int q = 0; q < 4; ++q)
                    scr[((l >> 4) * 4 + q) * 132 + ut * 16 + rr] =
                        (bt == 0) ? acc0[ut][q] : acc1[ut][q];
            const int gs = sb + w * 32 + bt * 16 + erow;
            const float kf = (gs == istar) ? 0.f : 128.f;
            #pragma unroll
            for (int j = 0; j < 8; ++j) {
                const float4 d = *(const float4*)&scr[erow * 132 + j * 16 + ecb];
                const float4 mv = *(const float4*)(mT + (size_t)gs * NU + uh * 128 + j * 16 + ecb);
                float4 o;
                o.x = d.x + kf * mv.x;
                o.y = d.y + kf * mv.y;
                o.z = d.z + kf * mv.z;
                o.w = d.w + kf * mv.w;
                *(float4*)(out + OUT_MEM + (size_t)gs * NU + uh * 128 + j * 16 + ecb) = o;
            }
        }
    }
}

// -------- K4b: read = c_wr.T @ m_tm1 via bf16 MFMA, LDS-staged transposed bf16 (R12) --------
template <int USE_PART>
__global__ __launch_bounds__(256) void k_read(
    const float* __restrict__ mT, float* __restrict__ out, float* __restrict__ part)
{
    __shared__ alignas(16) unsigned short cwrb[128 * 40];  // [b][m_local] bf16
    __shared__ alignas(16) unsigned short mb[128 * 40];    // [u_local][m_local] bf16
    const int t = threadIdx.x, w = t >> 6, l = t & 63;
    const int r = blockIdx.x, ri = r >> 1, uh = r & 1;
    const int rk = (l >> 4) * 8, rr = l & 15;
    const float* cwr = out + OUT_CWR;
    const int srow = t >> 3, sc = (t & 7) * 16;

    floatx4 acc[2][8];
    #pragma unroll
    for (int bt = 0; bt < 2; ++bt)
        #pragma unroll
        for (int ut = 0; ut < 8; ++ut) acc[bt][ut] = (floatx4){0.f, 0.f, 0.f, 0.f};

    for (int c = 0; c < 8; ++c) {
        const size_t m0 = (size_t)(ri * 256 + c * 32);
        #pragma unroll
        for (int q = 0; q < 4; ++q) {
            const float4 v = *(const float4*)(cwr + (m0 + srow) * NB + sc + q * 4);
            cwrb[(sc + q * 4 + 0) * 40 + srow] = f2b(v.x);
            cwrb[(sc + q * 4 + 1) * 40 + srow] = f2b(v.y);
            cwrb[(sc + q * 4 + 2) * 40 + srow] = f2b(v.z);
            cwrb[(sc + q * 4 + 3) * 40 + srow] = f2b(v.w);
            const float4 u = *(const float4*)(mT + (m0 + srow) * NU + uh * 128 + sc + q * 4);
            mb[(sc + q * 4 + 0) * 40 + srow] = f2b(u.x);
            mb[(sc + q * 4 + 1) * 40 + srow] = f2b(u.y);
            mb[(sc + q * 4 + 2) * 40 + srow] = f2b(u.z);
            mb[(sc + q * 4 + 3) * 40 + srow] = f2b(u.w);
        }
        __syncthreads();
        const short8v a0 = *(const short8v*)&cwrb[(w * 32 + rr) * 40 + rk];
        const short8v a1 = *(const short8v*)&cwrb[(w * 32 + 16 + rr) * 40 + rk];
        #pragma unroll
        for (int ut = 0; ut < 8; ++ut) {
            const short8v bf = *(const short8v*)&mb[(ut * 16 + rr) * 40 + rk];
            acc[0][ut] = __builtin_amdgcn_mfma_f32_16x16x32_bf16(a0, bf, acc[0][ut], 0, 0, 0);
            acc[1][ut] = __builtin_amdgcn_mfma_f32_16x16x32_bf16(a1, bf, acc[1][ut], 0, 0, 0);
        }
        __syncthreads();
    }

    // D mapping (m89-verified): col = l&15, row = (l>>4)*4 + q
    if (USE_PART) {
        float* dst = part + (size_t)r * (128 * 128);
        #pragma unroll
        for (int bt = 0; bt < 2; ++bt)
            #pragma unroll
            for (int ut = 0; ut < 8; ++ut)
                #pragma unroll
                for (int q = 0; q < 4; ++q)
                    dst[(size_t)(w * 32 + bt * 16 + (l >> 4) * 4 + q) * 128 + ut * 16 + rr] = acc[bt][ut][q];
    } else {
        #pragma unroll
        for (int bt = 0; bt < 2; ++bt)
            #pragma unroll
            for (int ut = 0; ut < 8; ++ut)
                #pragma unroll
                for (int q = 0; q < 4; ++q)
                    atomicAdd(out + OUT_READ + (size_t)(w * 32 + bt * 16 + (l >> 4) * 4 + q) * NU
                                  + uh * 128 + ut * 16 + rr, acc[bt][ut][q]);
    }
}

// ---------------- K5: deterministic read reduction ----------------
__global__ __launch_bounds__(256) void k_redread(const float* __restrict__ part,
                                                 float* __restrict__ out)
{
    const int b = blockIdx.x, u = threadIdx.x;
    const int uh = u >> 7, ul = u & 127;
    float s = 0.f;
    #pragma unroll 4
    for (int ri = 0; ri < 256; ++ri)
        s += part[((size_t)(ri * 2 + uh) * 128 + b) * 128 + ul];
    out[OUT_READ + b * NU + u] = s;
}

extern "C" void kernel_launch(void* const* d_in, const int* in_sizes, int n_in,
                              void* d_out, int out_size, void* d_ws, size_t ws_size,
                              hipStream_t stream)
{
    const float* inputs    = (const float*)d_in[0];
    const float* r_tm1     = (const float*)d_in[1];
    const float* m_tm1     = (const float*)d_in[2];
    const float* c_wu_tm1  = (const float*)d_in[3];
    const float* c_wlu_tm1 = (const float*)d_in[4];
    const float* c_wr_tm1  = (const float*)d_in[5];
    const float* h_tm1     = (const float*)d_in[6];
    const float* cc_tm1    = (const float*)d_in[7];
    const float* Wk        = (const float*)d_in[8];
    const float* Wr        = (const float*)d_in[9];
    const float* bias      = (const float*)d_in[10];
    const float* wgate     = (const float*)d_in[11];
    float* out = (float*)d_out;
    char* ws = (char*)d_ws;

    float* klnT = (float*)(ws + WS_KLNT);
    unsigned long long* minenc = (unsigned long long*)(ws + WS_MINENC);
    float* mins = (float*)(ws + WS_MINS);
    unsigned* istar = (unsigned*)(ws + WS_ISTAR);
    float* part = (float*)(ws + WS_PART);
    const bool use_part = ws_size >= WS_PART + (size_t)512 * 128 * 128 * 4;

    hipLaunchKernelGGL(k_lstm, dim3(128), dim3(256), 0, stream,
                       inputs, r_tm1, h_tm1, cc_tm1, Wk, Wr, bias, out, klnT, minenc);
    hipLaunchKernelGGL(k_dot, dim3(512), dim3(256), 0, stream,
                       m_tm1, klnT, c_wr_tm1, c_wlu_tm1, c_wu_tm1, wgate, out, minenc);
    hipLaunchKernelGGL(k_argmin, dim3(1), dim3(128), 0, stream, minenc, mins, istar);
    hipLaunchKernelGGL(k_mem, dim3(512), dim3(256), 0, stream,
                       m_tm1, c_wr_tm1, c_wlu_tm1, wgate, mins, istar, out);
    if (use_part) {
        hipLaunchKernelGGL((k_read<1>), dim3(512), dim3(256), 0, stream, m_tm1, out, part);
        hipLaunchKernelGGL(k_redread, dim3(128), dim3(256), 0, stream, part, out);
    } else {
        hipLaunchKernelGGL((k_read<0>), dim3(512), dim3(256), 0, stream, m_tm1, out, part);
    }
}

// Round 15
// 400.575 us; speedup vs baseline: 1.0463x; 1.0463x over previous
//
#include <hip/hip_runtime.h>
#include <hip/hip_bf16.h>
#include <math.h>

#define NM 65536
#define NB 128
#define NU 256
#define ND 512

// ---- output layout (flat f32, reference return order) ----
constexpr size_t OUT_READ = 0;                      // [B,U]    32768
constexpr size_t OUT_MEM  = 32768;                  // [M,U]    16777216
constexpr size_t OUT_CWU  = OUT_MEM + 16777216;     // [M,B]    8388608
constexpr size_t OUT_CWLU = OUT_CWU + 8388608;      // [M,B]
constexpr size_t OUT_CWR  = OUT_CWLU + 8388608;     // [M,B]
constexpr size_t OUT_KEY  = OUT_CWR + 8388608;      // [B,U]
constexpr size_t OUT_CC   = OUT_KEY + 32768;        // [B,U]

// ---- ws layout (bytes) ----
constexpr size_t WS_KLNT   = 0;        // 32768 f32 (klnT[u][b])
constexpr size_t WS_MINENC = 131072;   // 128 u64
constexpr size_t WS_MINS   = 132096;   // 128 f32
constexpr size_t WS_ISTAR  = 132608;   // 1 u32
constexpr size_t WS_PART   = 135168;   // 512 * 16384 f32 read-partials (32 MB)

typedef __attribute__((ext_vector_type(8))) short short8v;   // 8 bf16 (4 VGPRs)
typedef __attribute__((ext_vector_type(4))) float floatx4;

__device__ __forceinline__ unsigned fenc(float x) {
    unsigned u = __float_as_uint(x);
    return (u & 0x80000000u) ? ~u : (u | 0x80000000u);
}
__device__ __forceinline__ float fdec(unsigned e) {
    unsigned u = (e & 0x80000000u) ? (e ^ 0x80000000u) : ~e;
    return __uint_as_float(u);
}
__device__ __forceinline__ float sigm(float x) { return 1.0f / (1.0f + expf(-x)); }
__device__ __forceinline__ unsigned short f2b(float f) {
    __hip_bfloat16 h = __float2bfloat16(f);      // RNE
    return *reinterpret_cast<unsigned short*>(&h);
}

// ---------------- K1: LSTM controller + normalized keys (numerics anchor) ----------------
__global__ __launch_bounds__(256) void k_lstm(
    const float* __restrict__ xin_g, const float* __restrict__ r_tm1,
    const float* __restrict__ h_tm1, const float* __restrict__ cc_tm1,
    const float* __restrict__ Wk, const float* __restrict__ Wr,
    const float* __restrict__ bias, float* __restrict__ out,
    float* __restrict__ klnT, unsigned long long* __restrict__ minenc)
{
    const int b = blockIdx.x, t = threadIdx.x;
    __shared__ float xin[ND + NU];
    __shared__ float hh[NU];
    __shared__ float red[NU];
    for (int k = t; k < ND; k += 256) xin[k] = xin_g[b * ND + k];
    xin[ND + t] = r_tm1[b * NU + t];
    hh[t] = h_tm1[b * NU + t];
    out[OUT_READ + b * NU + t] = 0.f;              // zero read region each launch
    if (b == 0 && t < NB) minenc[t] = ~0ULL;       // init argmin atomics
    __syncthreads();

    float zi = bias[t], zf = bias[NU + t], zc = bias[2 * NU + t], zo = bias[3 * NU + t];
    #pragma unroll 4
    for (int k = 0; k < ND + NU; ++k) {
        const float x = xin[k];
        const float* w = Wk + (size_t)k * (4 * NU);
        zi += x * w[t]; zf += x * w[NU + t]; zc += x * w[2 * NU + t]; zo += x * w[3 * NU + t];
    }
    #pragma unroll 4
    for (int k = 0; k < NU; ++k) {
        const float x = hh[k];
        const float* w = Wr + (size_t)k * (4 * NU);
        zi += x * w[t]; zf += x * w[NU + t]; zc += x * w[2 * NU + t]; zo += x * w[3 * NU + t];
    }
    const float gi = sigm(zi), gf = sigm(zf), gc = tanhf(zc), go = sigm(zo);
    const float cold = cc_tm1[b * NU + t];
    const float cn = __fadd_rn(__fmul_rn(gf, cold), __fmul_rn(gi, gc));
    const float hn = __fmul_rn(go, tanhf(cn));
    out[OUT_KEY + b * NU + t] = hn;
    out[OUT_CC + b * NU + t] = cn;
    red[t] = hn * hn;
    __syncthreads();
    for (int s = 128; s > 0; s >>= 1) { if (t < s) red[t] += red[t + s]; __syncthreads(); }
    const float nrm = sqrtf(fmaxf(red[0], 1e-12f));
    klnT[t * NB + b] = hn / nrm;   // transposed [u][b]
}

// ------------- K2: fused norm + cosine GEMM + batch-softmax + usage + min (R11/R12 best) -------------
__global__ __launch_bounds__(256, 2) void k_dot(
    const float* __restrict__ mT, const float* __restrict__ klnT,
    const float* __restrict__ cwr_t, const float* __restrict__ cwlu_t,
    const float* __restrict__ cwu_t, const float* __restrict__ wgp,
    float* __restrict__ out, unsigned long long* __restrict__ minenc)
{
    __shared__ float smem[16384];      // 64 KB: stage tiles (32 KB), later dot tile [128][128]
    __shared__ float rn_s[128];
    const int t = threadIdx.x, w = t >> 6, l = t & 63;
    const int tx = t & 15, ty = t >> 4;
    const int b0a = tx * 4, b0b = 64 + tx * 4;   // split b-columns (conflict-free kv reads)
    const int s0 = ty * 8;
    const int sb = blockIdx.x * 128;

    // ---- phase 0: row norms (lane-l float4 + xor tree) ----
    #pragma unroll 4
    for (int i = 0; i < 32; ++i) {
        const int s = w * 32 + i;
        const float4 mv = *(const float4*)(mT + (size_t)(sb + s) * NU + l * 4);
        float ss = mv.x * mv.x + mv.y * mv.y + mv.z * mv.z + mv.w * mv.w;
        #pragma unroll
        for (int d = 1; d < 64; d <<= 1) ss += __shfl_xor(ss, d);
        if (l == 0) rn_s[s] = sqrtf(fmaxf(ss, 1e-12f));   // wave-private write/read
    }

    // ---- phase 1: GEMM dot[s][b] = sum_u m[s][u] * kln[u][b] ----
    const int sl = t & 127, ug = t >> 7;       // ms stage: slot sl, u-halves
    const int ku_ = t >> 4, kb = (t & 15) * 4; // kl stage

    float acc[8][8];
    #pragma unroll
    for (int i = 0; i < 8; ++i)
        #pragma unroll
        for (int j = 0; j < 8; ++j) acc[i][j] = 0.f;

    float4 gm[2], gk[2];
    #pragma unroll
    for (int i = 0; i < 2; ++i) {
        gm[i] = *(const float4*)(mT + (size_t)(sb + sl) * NU + (ug + 2 * i) * 4);
        gk[i] = *(const float4*)(klnT + (size_t)ku_ * NB + kb + i * 64);
    }
    for (int c = 0; c < 16; ++c) {
        const int mo = (c & 1) * 2048;          // ms buffer offset
        const int ko = 4096 + (c & 1) * 2048;   // kl buffer offset
        #pragma unroll
        for (int i = 0; i < 2; ++i) {
            const int uo = (ug + 2 * i) * 4;
            smem[mo + (uo + 0) * 128 + sl] = gm[i].x;
            smem[mo + (uo + 1) * 128 + sl] = gm[i].y;
            smem[mo + (uo + 2) * 128 + sl] = gm[i].z;
            smem[mo + (uo + 3) * 128 + sl] = gm[i].w;
            *(float4*)&smem[ko + ku_ * 128 + kb + i * 64] = gk[i];
        }
        __syncthreads();
        if (c < 15) {   // prefetch next chunk into registers (overlaps compute)
            const int uc = (c + 1) * 16;
            #pragma unroll
            for (int i = 0; i < 2; ++i) {
                gm[i] = *(const float4*)(mT + (size_t)(sb + sl) * NU + uc + (ug + 2 * i) * 4);
                gk[i] = *(const float4*)(klnT + (size_t)(uc + ku_) * NB + kb + i * 64);
            }
        }
        #pragma unroll 4
        for (int u = 0; u < 16; ++u) {
            const float4 sv0 = *(const float4*)&smem[mo + u * 128 + s0];
            const float4 sv1 = *(const float4*)&smem[mo + u * 128 + s0 + 4];
            const float4 kv0 = *(const float4*)&smem[ko + u * 128 + b0a];   // 256B run: conflict-free
            const float4 kv1 = *(const float4*)&smem[ko + u * 128 + b0b];   // 256B run: conflict-free
            const float sv[8] = {sv0.x, sv0.y, sv0.z, sv0.w, sv1.x, sv1.y, sv1.z, sv1.w};
            const float kv[8] = {kv0.x, kv0.y, kv0.z, kv0.w, kv1.x, kv1.y, kv1.z, kv1.w};
            #pragma unroll
            for (int i = 0; i < 8; ++i)
                #pragma unroll
                for (int j = 0; j < 8; ++j)
                    acc[i][j] += sv[i] * kv[j];   // single fmac chain ascending u per (s,b)
        }
        __syncthreads();
    }

    // ---- phase 2: spill dot tile to LDS (aliases stage buffers; barrier-protected) ----
    #pragma unroll
    for (int i = 0; i < 8; ++i) {
        *(float4*)&smem[(s0 + i) * 128 + b0a] = make_float4(acc[i][0], acc[i][1], acc[i][2], acc[i][3]);
        *(float4*)&smem[(s0 + i) * 128 + b0b] = make_float4(acc[i][4], acc[i][5], acc[i][6], acc[i][7]);
    }
    __syncthreads();

    // ---- phase 3: per-slot softmax + usage + min (lane = b-pair) ----
    const float wg = sigm(wgp[0]);
    const float omw = __fsub_rn(1.f, wg);
    unsigned long long lmin0 = ~0ULL, lmin1 = ~0ULL;
    #pragma unroll 2
    for (int i = 0; i < 32; ++i) {
        const int s = w * 32 + i;
        const int m = sb + s;
        const float2 dv = *(const float2*)&smem[s * 128 + 2 * l];
        const float rnv = rn_s[s];
        const float2 wrt = ((const float2*)(cwr_t + (size_t)m * NB))[l];
        const float2 wlu = ((const float2*)(cwlu_t + (size_t)m * NB))[l];
        const float2 wut = ((const float2*)(cwu_t + (size_t)m * NB))[l];
        const float c0 = dv.x / rnv, c1 = dv.y / rnv;
        float mx = fmaxf(c0, c1);
        #pragma unroll
        for (int d = 1; d < 64; d <<= 1) mx = fmaxf(mx, __shfl_xor(mx, d));
        const float e0 = expf(c0 - mx), e1 = expf(c1 - mx);
        float sm = e0 + e1;
        #pragma unroll
        for (int d = 1; d < 64; d <<= 1) sm += __shfl_xor(sm, d);
        const float w0 = e0 / sm, w1 = e1 / sm;
        const float cww0 = __fadd_rn(__fadd_rn(__fmul_rn(wg, wrt.x), omw), wlu.x);
        const float cww1 = __fadd_rn(__fadd_rn(__fmul_rn(wg, wrt.y), omw), wlu.y);
        const float cu0 = __fadd_rn(__fadd_rn(__fmul_rn(0.95f, wut.x), w0), cww0);
        const float cu1 = __fadd_rn(__fadd_rn(__fmul_rn(0.95f, wut.y), w1), cww1);
        ((float2*)(out + OUT_CWR))[(size_t)m * 64 + l] = make_float2(w0, w1);
        ((float2*)(out + OUT_CWU))[(size_t)m * 64 + l] = make_float2(cu0, cu1);
        const unsigned long long e0u = (((unsigned long long)fenc(cu0)) << 32) | (unsigned)m;
        const unsigned long long e1u = (((unsigned long long)fenc(cu1)) << 32) | (unsigned)m;
        lmin0 = (e0u < lmin0) ? e0u : lmin0;
        lmin1 = (e1u < lmin1) ? e1u : lmin1;
    }
    atomicMin(&minenc[2 * l], lmin0);
    atomicMin(&minenc[2 * l + 1], lmin1);
}

// ---------------- K3: global argmin (first-occurrence) ----------------
__global__ void k_argmin(const unsigned long long* __restrict__ minenc,
                         float* __restrict__ mins, unsigned* __restrict__ istar)
{
    __shared__ unsigned long long red[NB];
    const int t = threadIdx.x;
    const unsigned long long e = minenc[t];
    const unsigned enc32 = (unsigned)(e >> 32);
    mins[t] = fdec(enc32);
    red[t] = (((unsigned long long)enc32) << 32) | (unsigned)t;
    __syncthreads();
    for (int s = 64; s > 0; s >>= 1) {
        if (t < s) { const unsigned long long o = red[t + s]; if (o < red[t]) red[t] = o; }
        __syncthreads();
    }
    if (t == 0) {
        const unsigned bstar = (unsigned)(red[0] & 0xFFFFFFFFu);
        istar[0] = (unsigned)(minenc[bstar] & 0xFFFFFFFFu);
    }
}

// -------- K4a: memory = cww @ key (bf16 MFMA) + 128*keep*m (f32) + c_wlu (R12) --------
__global__ __launch_bounds__(256, 2) void k_mem(
    const float* __restrict__ mT,
    const float* __restrict__ cwr_t, const float* __restrict__ cwlu_t,
    const float* __restrict__ wgp, const float* __restrict__ mins,
    const unsigned* __restrict__ istar_p, float* __restrict__ out)
{
    __shared__ alignas(16) unsigned short cwwb[128 * 136];   // [s][b] bf16, stride 136
    __shared__ alignas(16) unsigned short keyT[128 * 136];   // [u_local][b] bf16; reused as f32 scratch
    const int t = threadIdx.x, w = t >> 6, l = t & 63;
    const int sb = blockIdx.x * 128;
    const float wg = sigm(wgp[0]);
    const float omw = __fsub_rn(1.f, wg);
    const int istar = (int)istar_p[0];

    // ---- S1: cww -> bf16 LDS; c_wlu -> global (exact f32 chain) ----
    {
        const int srow = t >> 5;
        const int bc = (t & 31) * 4;
        for (int it = 0; it < 16; ++it) {
            const int s = it * 8 + srow;
            const size_t row = (size_t)(sb + s) * NB + bc;
            const float4 wr = *(const float4*)(cwr_t + row);
            const float4 lu = *(const float4*)(cwlu_t + row);
            const float4 wu = *(const float4*)(out + OUT_CWU + row);
            float4 cw;
            cw.x = __fadd_rn(__fadd_rn(__fmul_rn(wg, wr.x), omw), lu.x);
            cw.y = __fadd_rn(__fadd_rn(__fmul_rn(wg, wr.y), omw), lu.y);
            cw.z = __fadd_rn(__fadd_rn(__fmul_rn(wg, wr.z), omw), lu.z);
            cw.w = __fadd_rn(__fadd_rn(__fmul_rn(wg, wr.w), omw), lu.w);
            ushort4 pk;
            pk.x = f2b(cw.x); pk.y = f2b(cw.y); pk.z = f2b(cw.z); pk.w = f2b(cw.w);
            *(ushort4*)&cwwb[s * 136 + bc] = pk;
            const float4 mb = *(const float4*)(mins + bc);
            float4 wl;
            wl.x = (wu.x <= mb.x) ? 1.f : 0.f;
            wl.y = (wu.y <= mb.y) ? 1.f : 0.f;
            wl.z = (wu.z <= mb.z) ? 1.f : 0.f;
            wl.w = (wu.w <= mb.w) ? 1.f : 0.f;
            *(float4*)(out + OUT_CWLU + row) = wl;
        }
    }

    const int rk = (l >> 4) * 8;
    const int rr = l & 15;

    for (int uh = 0; uh < 2; ++uh) {
        if (uh) __syncthreads();     // epilogue scratch reads done before re-staging keyT
        // ---- S2: keyT half uh: key[b][u] f32 -> bf16 LDS [u_local][b] ----
        {
            const int br = t >> 5;
            const int ko = (t & 31) * 4;
            for (int it = 0; it < 16; ++it) {
                const int b = it * 8 + br;
                const float4 kv = *(const float4*)(out + OUT_KEY + (size_t)b * NU + uh * 128 + ko);
                keyT[(ko + 0) * 136 + b] = f2b(kv.x);
                keyT[(ko + 1) * 136 + b] = f2b(kv.y);
                keyT[(ko + 2) * 136 + b] = f2b(kv.z);
                keyT[(ko + 3) * 136 + b] = f2b(kv.w);
            }
        }
        __syncthreads();

        // ---- MFMA: wave w -> s-tiles {2w, 2w+1}; 8 u-tiles; K=128 in 4 chunks ----
        floatx4 acc0[8], acc1[8];
        #pragma unroll
        for (int ut = 0; ut < 8; ++ut) {
            acc0[ut] = (floatx4){0.f, 0.f, 0.f, 0.f};
            acc1[ut] = (floatx4){0.f, 0.f, 0.f, 0.f};
        }
        #pragma unroll
        for (int kc = 0; kc < 4; ++kc) {
            const short8v a0 = *(const short8v*)&cwwb[(w * 32 + rr) * 136 + kc * 32 + rk];
            const short8v a1 = *(const short8v*)&cwwb[(w * 32 + 16 + rr) * 136 + kc * 32 + rk];
            #pragma unroll
            for (int ut = 0; ut < 8; ++ut) {
                const short8v bf = *(const short8v*)&keyT[(ut * 16 + rr) * 136 + kc * 32 + rk];
                acc0[ut] = __builtin_amdgcn_mfma_f32_16x16x32_bf16(a0, bf, acc0[ut], 0, 0, 0);
                acc1[ut] = __builtin_amdgcn_mfma_f32_16x16x32_bf16(a1, bf, acc1[ut], 0, 0, 0);
            }
        }

        // ---- epilogue: transpose D via per-wave scratch (keyT region), float4 I/O ----
        __syncthreads();                           // all waves done reading keyT
        float* scr = (float*)keyT + w * 2112;      // [16][132] f32, wave-private
        const int erow = l >> 2, ecb = (l & 3) * 4;
        #pragma unroll
        for (int bt = 0; bt < 2; ++bt) {
            #pragma unroll
            for (int ut = 0; ut < 8; ++ut)
                #pragma unroll
                for (int q = 0; q < 4; ++q)
                    scr[((l >> 4) * 4 + q) * 132 + ut * 16 + rr] =
                        (bt == 0) ? acc0[ut][q] : acc1[ut][q];
            const int gs = sb + w * 32 + bt * 16 + erow;
            const float kf = (gs == istar) ? 0.f : 128.f;
            #pragma unroll
            for (int j = 0; j < 8; ++j) {
                const float4 d = *(const float4*)&scr[erow * 132 + j * 16 + ecb];
                const float4 mv = *(const float4*)(mT + (size_t)gs * NU + uh * 128 + j * 16 + ecb);
                float4 o;
                o.x = d.x + kf * mv.x;
                o.y = d.y + kf * mv.y;
                o.z = d.z + kf * mv.z;
                o.w = d.w + kf * mv.w;
                *(float4*)(out + OUT_MEM + (size_t)gs * NU + uh * 128 + j * 16 + ecb) = o;
            }
        }
    }
}

// -------- K4b: read = c_wr.T @ m_tm1 via bf16 MFMA, LDS-staged transposed bf16 (R12) --------
template <int USE_PART>
__global__ __launch_bounds__(256) void k_read(
    const float* __restrict__ mT, float* __restrict__ out, float* __restrict__ part)
{
    __shared__ alignas(16) unsigned short cwrb[128 * 40];  // [b][m_local] bf16
    __shared__ alignas(16) unsigned short mb[128 * 40];    // [u_local][m_local] bf16
    const int t = threadIdx.x, w = t >> 6, l = t & 63;
    const int r = blockIdx.x, ri = r >> 1, uh = r & 1;
    const int rk = (l >> 4) * 8, rr = l & 15;
    const float* cwr = out + OUT_CWR;
    const int srow = t >> 3, sc = (t & 7) * 16;

    floatx4 acc[2][8];
    #pragma unroll
    for (int bt = 0; bt < 2; ++bt)
        #pragma unroll
        for (int ut = 0; ut < 8; ++ut) acc[bt][ut] = (floatx4){0.f, 0.f, 0.f, 0.f};

    for (int c = 0; c < 8; ++c) {
        const size_t m0 = (size_t)(ri * 256 + c * 32);
        #pragma unroll
        for (int q = 0; q < 4; ++q) {
            const float4 v = *(const float4*)(cwr + (m0 + srow) * NB + sc + q * 4);
            cwrb[(sc + q * 4 + 0) * 40 + srow] = f2b(v.x);
            cwrb[(sc + q * 4 + 1) * 40 + srow] = f2b(v.y);
            cwrb[(sc + q * 4 + 2) * 40 + srow] = f2b(v.z);
            cwrb[(sc + q * 4 + 3) * 40 + srow] = f2b(v.w);
            const float4 u = *(const float4*)(mT + (m0 + srow) * NU + uh * 128 + sc + q * 4);
            mb[(sc + q * 4 + 0) * 40 + srow] = f2b(u.x);
            mb[(sc + q * 4 + 1) * 40 + srow] = f2b(u.y);
            mb[(sc + q * 4 + 2) * 40 + srow] = f2b(u.z);
            mb[(sc + q * 4 + 3) * 40 + srow] = f2b(u.w);
        }
        __syncthreads();
        const short8v a0 = *(const short8v*)&cwrb[(w * 32 + rr) * 40 + rk];
        const short8v a1 = *(const short8v*)&cwrb[(w * 32 + 16 + rr) * 40 + rk];
        #pragma unroll
        for (int ut = 0; ut < 8; ++ut) {
            const short8v bf = *(const short8v*)&mb[(ut * 16 + rr) * 40 + rk];
            acc[0][ut] = __builtin_amdgcn_mfma_f32_16x16x32_bf16(a0, bf, acc[0][ut], 0, 0, 0);
            acc[1][ut] = __builtin_amdgcn_mfma_f32_16x16x32_bf16(a1, bf, acc[1][ut], 0, 0, 0);
        }
        __syncthreads();
    }

    // D mapping (m89-verified): col = l&15, row = (l>>4)*4 + q
    if (USE_PART) {
        float* dst = part + (size_t)r * (128 * 128);
        #pragma unroll
        for (int bt = 0; bt < 2; ++bt)
            #pragma unroll
            for (int ut = 0; ut < 8; ++ut)
                #pragma unroll
                for (int q = 0; q < 4; ++q)
                    dst[(size_t)(w * 32 + bt * 16 + (l >> 4) * 4 + q) * 128 + ut * 16 + rr] = acc[bt][ut][q];
    } else {
        #pragma unroll
        for (int bt = 0; bt < 2; ++bt)
            #pragma unroll
            for (int ut = 0; ut < 8; ++ut)
                #pragma unroll
                for (int q = 0; q < 4; ++q)
                    atomicAdd(out + OUT_READ + (size_t)(w * 32 + bt * 16 + (l >> 4) * 4 + q) * NU
                                  + uh * 128 + ut * 16 + rr, acc[bt][ut][q]);
    }
}

// ---------------- K5: deterministic read reduction ----------------
__global__ __launch_bounds__(256) void k_redread(const float* __restrict__ part,
                                                 float* __restrict__ out)
{
    const int b = blockIdx.x, u = threadIdx.x;
    const int uh = u >> 7, ul = u & 127;
    float s = 0.f;
    #pragma unroll 4
    for (int ri = 0; ri < 256; ++ri)
        s += part[((size_t)(ri * 2 + uh) * 128 + b) * 128 + ul];
    out[OUT_READ + b * NU + u] = s;
}

extern "C" void kernel_launch(void* const* d_in, const int* in_sizes, int n_in,
                              void* d_out, int out_size, void* d_ws, size_t ws_size,
                              hipStream_t stream)
{
    const float* inputs    = (const float*)d_in[0];
    const float* r_tm1     = (const float*)d_in[1];
    const float* m_tm1     = (const float*)d_in[2];
    const float* c_wu_tm1  = (const float*)d_in[3];
    const float* c_wlu_tm1 = (const float*)d_in[4];
    const float* c_wr_tm1  = (const float*)d_in[5];
    const float* h_tm1     = (const float*)d_in[6];
    const float* cc_tm1    = (const float*)d_in[7];
    const float* Wk        = (const float*)d_in[8];
    const float* Wr        = (const float*)d_in[9];
    const float* bias      = (const float*)d_in[10];
    const float* wgate     = (const float*)d_in[11];
    float* out = (float*)d_out;
    char* ws = (char*)d_ws;

    float* klnT = (float*)(ws + WS_KLNT);
    unsigned long long* minenc = (unsigned long long*)(ws + WS_MINENC);
    float* mins = (float*)(ws + WS_MINS);
    unsigned* istar = (unsigned*)(ws + WS_ISTAR);
    float* part = (float*)(ws + WS_PART);
    const bool use_part = ws_size >= WS_PART + (size_t)512 * 128 * 128 * 4;

    hipLaunchKernelGGL(k_lstm, dim3(128), dim3(256), 0, stream,
                       inputs, r_tm1, h_tm1, cc_tm1, Wk, Wr, bias, out, klnT, minenc);
    hipLaunchKernelGGL(k_dot, dim3(512), dim3(256), 0, stream,
                       m_tm1, klnT, c_wr_tm1, c_wlu_tm1, c_wu_tm1, wgate, out, minenc);
    hipLaunchKernelGGL(k_argmin, dim3(1), dim3(128), 0, stream, minenc, mins, istar);
    hipLaunchKernelGGL(k_mem, dim3(512), dim3(256), 0, stream,
                       m_tm1, c_wr_tm1, c_wlu_tm1, wgate, mins, istar, out);
    if (use_part) {
        hipLaunchKernelGGL((k_read<1>), dim3(512), dim3(256), 0, stream, m_tm1, out, part);
        hipLaunchKernelGGL(k_redread, dim3(128), dim3(256), 0, stream, part, out);
    } else {
        hipLaunchKernelGGL((k_read<0>), dim3(512), dim3(256), 0, stream, m_tm1, out, part);
    }
}